// Round 13
// baseline (670.849 us; speedup 1.0000x reference)
//
#include <hip/hip_runtime.h>
#include <stdint.h>

#define E_DIM 1024
#define H_NUM 16
#define B_NUM 8
#define LQ 1024
#define LK 1024
#define MROWS (B_NUM * LQ)   // 8192

typedef unsigned short u16;
typedef __attribute__((ext_vector_type(8))) short bf16x8;
typedef __attribute__((ext_vector_type(4))) short bf16x4;
typedef __attribute__((ext_vector_type(4))) float f32x4;
typedef __attribute__((ext_vector_type(2))) unsigned int u32x2;
typedef bf16x8 __attribute__((may_alias)) bf16x8_ma;
typedef bf16x4 __attribute__((may_alias)) bf16x4_ma;
typedef f32x4 __attribute__((may_alias)) f32x4_ma;
typedef u32x2 __attribute__((may_alias)) u32x2_ma;

typedef __attribute__((address_space(1))) const void* gas_ptr;
typedef __attribute__((address_space(3))) void* las_ptr;

__device__ __forceinline__ void gload16(const void* g, void* l) {
  __builtin_amdgcn_global_load_lds((gas_ptr)g, (las_ptr)l, 16, 0, 0);
}

__device__ __forceinline__ u16 f2bf(float f) {
  union { float f; uint32_t u; } c; c.f = f;
  return (u16)((c.u + 0x7FFFu + ((c.u >> 16) & 1u)) >> 16);
}

// pack two f32 -> two bf16 (truncation) in one v_perm
__device__ __forceinline__ uint32_t pack2bf(float lo, float hi) {
  return __builtin_amdgcn_perm(__float_as_uint(hi), __float_as_uint(lo), 0x07060302u);
}

#define MFMA_BF16(a, b, c) __builtin_amdgcn_mfma_f32_16x16x32_bf16((a), (b), (c), 0, 0, 0)

// Q scale: 1/sqrt(64) * log2(e), folded into Qb so attn kernels use exp2 directly
#define SCALE_Q 0.18033688011112042f

// NOTES from this session's post-mortems:
//  R8:  no XOR swizzles on pad-72 attn LDS tiles (pad-72 already bank-minimal).
//  R11: BK=32 ring-4 with 128K LDS regressed (1 block/CU, more barriers).
//  R12: barrier-halving at 1 block/CU is null -> gemm0 was limited by
//       single-block residency (no cross-block stall hiding + 2-round packing),
//       not by intra-block schedule. Fix: 64K LDS -> 2 blocks/CU.

// ---------------------------------------------------------------- cvt f32->bf16 (single src)
__global__ __launch_bounds__(256) void cvt_f32_bf16(const float* __restrict__ src,
                                                    u16* __restrict__ dst, int n4) {
  int i = blockIdx.x * 256 + threadIdx.x;
  const int stride = gridDim.x * 256;
  for (; i < n4; i += stride) {
    float4 v = ((const float4*)src)[i];
    ushort4 o;
    o.x = f2bf(v.x); o.y = f2bf(v.y); o.z = f2bf(v.z); o.w = f2bf(v.w);
    ((ushort4*)dst)[i] = o;
  }
}

// cvt for 3 equal-size buffers via blockIdx.y
__global__ __launch_bounds__(256) void cvt3_f32_bf16(
    const float* __restrict__ a0, const float* __restrict__ a1, const float* __restrict__ a2,
    u16* __restrict__ o0, u16* __restrict__ o1, u16* __restrict__ o2, int n4) {
  const float* s = (blockIdx.y == 0) ? a0 : (blockIdx.y == 1 ? a1 : a2);
  u16* d = (blockIdx.y == 0) ? o0 : (blockIdx.y == 1 ? o1 : o2);
  int i = blockIdx.x * 256 + threadIdx.x;
  const int stride = gridDim.x * 256;
  for (; i < n4; i += stride) {
    float4 v = ((const float4*)s)[i];
    ushort4 o;
    o.x = f2bf(v.x); o.y = f2bf(v.y); o.z = f2bf(v.z); o.w = f2bf(v.w);
    ((ushort4*)d)[i] = o;
  }
}

// ---------------------------------------------------------------- QKV GEMM: 256x256, BK=32,
// double-buffered 64 KiB LDS -> 2 blocks/CU (cross-block stall hiding, all 384 resident).
// m97-style loop: stage next buf, read frags, 32 MFMA, one __syncthreads per K-step.
// Layout [128 rows x 32 cols] halves: frag reads are bank-uniform -> no swizzle anywhere;
// global_load_lds staging is purely linear (dest = base + tid*16 <-> row=tid>>2, chunk=tid&3).

#define STG(t, buf) do {                                                     \
    const size_t kc = (size_t)(t) * 32;                                      \
    gload16(pA0 + kc, ldsv + (buf) * 16384 + segoff);                        \
    gload16(pA1 + kc, ldsv + (buf) * 16384 + 8192 + segoff);                 \
    gload16(pB0 + kc, ldsv + 32768 + (buf) * 16384 + segoff);                \
    gload16(pB1 + kc, ldsv + 32768 + (buf) * 16384 + 8192 + segoff);         \
  } while (0)

#define RDQ(buf)                                                             \
  _Pragma("unroll") for (int j = 0; j < 8; ++j) {                            \
    const int rga = 2 * j + wm;                                              \
    av[j] = *(const bf16x8_ma*)(ldsc + (buf) * 16384 + ((rga >> 3) << 13) +  \
                                ((rga & 7) << 10) + lr * 64 + lg * 16);      \
  }                                                                          \
  _Pragma("unroll") for (int n = 0; n < 4; ++n) {                            \
    const int rgb = wn4 + n;                                                 \
    bv[n] = *(const bf16x8_ma*)(ldsc + 32768 + (buf) * 16384 +               \
                                ((rgb >> 3) << 13) + ((rgb & 7) << 10) +     \
                                lr * 64 + lg * 16);                          \
  }

#define MMAQ()                                                               \
  _Pragma("unroll") for (int j = 0; j < 8; ++j)                              \
    _Pragma("unroll") for (int n = 0; n < 4; ++n)                            \
      acc[j][n] = MFMA_BF16(av[j], bv[n], acc[j][n]);

__global__ __launch_bounds__(512, 4) void gemm_qkv(
    const u16* __restrict__ A0, const u16* __restrict__ A1, const u16* __restrict__ A2,
    const u16* __restrict__ W, const float* __restrict__ bias,
    u16* __restrict__ outb, int nwg_n, int nwg_m) {
  __shared__ u16 lds[32768];  // 64 KiB: A db0|db1 [0,32K), B db0|db1 [32K,64K)

  const int tid = threadIdx.x;
  const int wave = tid >> 6, lane = tid & 63;
  const int lr = lane & 15, lg = lane >> 4;
  const int wm = wave >> 2, wn4 = (wave & 3) * 4;

  // XCD swizzle (grid % 8 == 0); n-fastest so A-panels stay XCD-local
  const int cpx = (int)gridDim.x >> 3;
  const int bid = blockIdx.x;
  const int wg = (bid & 7) * cpx + (bid >> 3);
  const int n_i = wg % nwg_n;
  const int rest = wg / nwg_n;
  const int m_i = rest % nwg_m;
  const int z = rest / nwg_m;
  const int m0 = m_i * 256, n0 = n_i * 256;

  const u16* Az = (z == 0) ? A0 : (z == 1 ? A1 : A2);
  const u16* Wz = W + (size_t)z * E_DIM * E_DIM;
  const float* bs = bias + z * E_DIM;
  const float scale = (z == 0) ? SCALE_Q : 1.0f;

  // staging pointers: thread stages row tid>>2 (of each 128-row half), col (tid&3)*8
  const int grow = tid >> 2;
  const int gcol = (tid & 3) * 8;
  const u16* pA0 = Az + (size_t)(m0 + grow) * E_DIM + gcol;
  const u16* pA1 = Az + (size_t)(m0 + 128 + grow) * E_DIM + gcol;
  const u16* pB0 = Wz + (size_t)(n0 + grow) * E_DIM + gcol;
  const u16* pB1 = Wz + (size_t)(n0 + 128 + grow) * E_DIM + gcol;
  char* ldsv = (char*)lds;
  const char* ldsc = (const char*)lds;
  const int segoff = tid * 16;   // = wave*1024 (uniform) + lane*16

  const f32x4 fzero = {0.f, 0.f, 0.f, 0.f};
  f32x4 acc[8][4];
#pragma unroll
  for (int j = 0; j < 8; ++j)
#pragma unroll
    for (int n = 0; n < 4; ++n) acc[j][n] = fzero;

  bf16x8 av[8], bv[4];

  // prologue: tile 0 -> buf 0
  STG(0, 0);
  __syncthreads();   // drains vmcnt -> tile 0 visible

#pragma unroll 1
  for (int t = 0; t < 32; t += 2) {
    // even step: compute buf0, stage tile t+1 -> buf1 (t+1 <= 31 always)
    STG(t + 1, 1);
    RDQ(0)
    MMAQ()
    __syncthreads();   // staging done + buf0 reads retired
    // odd step: compute buf1, stage tile t+2 -> buf0
    if (t < 30) STG(t + 2, 0);
    RDQ(1)
    MMAQ()
    __syncthreads();
  }

  float bvv[4];
#pragma unroll
  for (int n = 0; n < 4; ++n) bvv[n] = bs[n0 + wn4 * 16 + n * 16 + lr];

  u16* Cb = outb + (size_t)z * (size_t)MROWS * E_DIM;
#pragma unroll
  for (int j = 0; j < 8; ++j) {
    const int rbase = m0 + (2 * j + wm) * 16 + lg * 4;
#pragma unroll
    for (int ii = 0; ii < 4; ++ii) {
      const size_t m = (size_t)(rbase + ii);
#pragma unroll
      for (int n = 0; n < 4; ++n) {
        const int nn = n0 + wn4 * 16 + n * 16 + lr;
        Cb[m * E_DIM + nn] = f2bf((acc[j][n][ii] + bvv[n]) * scale);
      }
    }
  }
}

// ---------------------------------------------------------------- 128x128 2-phase GEMM (out-proj)
// C = A @ W^T + bias + resid (f32 out). 512 blocks -> full machine (~520 TF structure).
__global__ __launch_bounds__(256) void gemm128_out(
    const u16* __restrict__ A, const u16* __restrict__ W,
    const float* __restrict__ bias, const float* __restrict__ resid,
    float* __restrict__ outf, int nwg_n, int nwg_m) {
  __shared__ u16 As[128 * 64];
  __shared__ u16 Bs[128 * 64];

  const int tid = threadIdx.x;
  const int wave = tid >> 6;
  const int lane = tid & 63;
  const int lr = lane & 15, lg = lane >> 4;
  const int wr = wave >> 1, wc = wave & 1;

  const int cpx = (int)gridDim.x >> 3;
  const int bid = blockIdx.x;
  const int wg = (bid & 7) * cpx + (bid >> 3);
  const int n_i = wg % nwg_n;
  const int m_i = (wg / nwg_n) % nwg_m;

  const int m0 = m_i * 128;
  const int n0 = n_i * 128;

  const f32x4 fzero = {0.f, 0.f, 0.f, 0.f};
  f32x4 acc[4][4];
#pragma unroll
  for (int a = 0; a < 4; ++a)
#pragma unroll
    for (int b = 0; b < 4; ++b) acc[a][b] = fzero;

  const int lrow8 = lane >> 3;        // 0..7
  const int lcol8 = (lane & 7) * 8;   // 0..56

  for (int kt = 0; kt < E_DIM; kt += 64) {
#pragma unroll
    for (int i = 0; i < 4; ++i) {
      const int seg = i * 4 + wave;   // 0..15, each covers 1024 B (8 rows)
      gload16(W + (size_t)(n0 + seg * 8 + lrow8) * E_DIM + kt + lcol8, &Bs[seg * 512]);
      gload16(A + (size_t)(m0 + seg * 8 + lrow8) * E_DIM + kt + lcol8, &As[seg * 512]);
    }
    __syncthreads();

#pragma unroll
    for (int kk = 0; kk < 64; kk += 32) {
      bf16x8 av[4], bv[4];
#pragma unroll
      for (int t = 0; t < 4; ++t)
        av[t] = *(const bf16x8*)&As[(wr * 64 + t * 16 + lr) * 64 + kk + lg * 8];
#pragma unroll
      for (int t = 0; t < 4; ++t)
        bv[t] = *(const bf16x8*)&Bs[(wc * 64 + t * 16 + lr) * 64 + kk + lg * 8];
#pragma unroll
      for (int mi = 0; mi < 4; ++mi)
#pragma unroll
        for (int ni = 0; ni < 4; ++ni)
          acc[mi][ni] = MFMA_BF16(av[mi], bv[ni], acc[mi][ni]);
    }
    __syncthreads();
  }

  float bvv[4];
#pragma unroll
  for (int ni = 0; ni < 4; ++ni) bvv[ni] = bias[n0 + wc * 64 + ni * 16 + lr];

#pragma unroll
  for (int mi = 0; mi < 4; ++mi) {
#pragma unroll
    for (int i = 0; i < 4; ++i) {
      const size_t m = (size_t)(m0 + wr * 64 + mi * 16 + lg * 4 + i);
#pragma unroll
      for (int ni = 0; ni < 4; ++ni) {
        const int n = n0 + wc * 64 + ni * 16 + lr;
        outf[m * E_DIM + n] = acc[mi][ni][i] + bvv[ni] + resid[m * E_DIM + n];
      }
    }
  }
}

// ---------------------------------------------------------------- V transpose (once)
// Vb (b,k,h*64+d) -> Vtg[(b*16+h)*64 + d][k]
__global__ __launch_bounds__(256) void transpose_v(const u16* __restrict__ Vb,
                                                   u16* __restrict__ Vtg) {
  __shared__ u16 T[64 * 264];
  const int tid = threadIdx.x;
  const int b = blockIdx.z, h = blockIdx.y;
  const int k0 = blockIdx.x * 256;
  const int bh = b * H_NUM + h;
  const int krow = tid >> 3;          // 0..31
  const int d0 = (tid & 7) * 8;
  const int jst = krow & 7;           // stagger to spread banks
#pragma unroll
  for (int it = 0; it < 8; ++it) {
    const int k = it * 32 + krow;
    bf16x8 v = *(const bf16x8*)&Vb[(size_t)(b * LK + k0 + k) * E_DIM + h * 64 + d0];
#pragma unroll
    for (int jj = 0; jj < 8; ++jj) {
      const int j = (jj + jst) & 7;
      T[(d0 + j) * 264 + k] = (u16)v[j];
    }
  }
  __syncthreads();
  const int d = tid >> 2;
  const int kk0 = (tid & 3) * 64;
  u16* orow = &Vtg[(size_t)(bh * 64 + d) * LK + k0 + kk0];
#pragma unroll
  for (int c = 0; c < 8; ++c)
    *(bf16x8*)&orow[c * 8] = *(const bf16x8*)&T[d * 264 + kk0 + c * 8];
}

// ---------------------------------------------------------------- attention fwd (swapped QK^T)
// per (b, h, 128-row q-tile); 8 waves x 16 q-rows each. |S|<~5 -> no max subtraction.
// Plain pad-72 LDS; pack2bf truncation for P. Stores rden = 0.0625/denom.
__global__ __launch_bounds__(512) void attn_fwd(
    const u16* __restrict__ Qb, const u16* __restrict__ Kb, const u16* __restrict__ Vtg,
    u16* __restrict__ attnb, float* __restrict__ rden) {
  __shared__ u16 Ks[64 * 72];
  __shared__ u16 Vt[64 * 72];
  __shared__ u16 Pw[8][16 * 72];

  const int tid = threadIdx.x;
  const int wave = tid >> 6, lane = tid & 63;
  const int lr = lane & 15, lg = lane >> 4;

  // XCD swizzle: 1024 blocks, 128/XCD = one full b; consecutive 8 blocks share (b,h)
  const int bid = blockIdx.x;
  const int wg = (bid & 7) * 128 + (bid >> 3);
  const int qt = wg & 7;
  const int h = (wg >> 3) & 15;
  const int b = wg >> 7;
  const int bh = b * H_NUM + h;
  const int q0 = qt * 128;

  const size_t qoff = (size_t)(b * LQ + q0 + wave * 16 + lr) * E_DIM + h * 64;
  const bf16x8 qf0 = *(const bf16x8*)&Qb[qoff + lg * 8];
  const bf16x8 qf1 = *(const bf16x8*)&Qb[qoff + 32 + lg * 8];

  const f32x4 fzero = {0.f, 0.f, 0.f, 0.f};
  f32x4 ctx[4];
#pragma unroll
  for (int d = 0; d < 4; ++d) ctx[d] = fzero;
  float dnl = 0.f;

  const int sr = tid >> 3;        // 0..63
  const int sc = (tid & 7) * 8;   // 0..56
  const u16* Kg = &Kb[(size_t)(b * LK + sr) * E_DIM + h * 64 + sc];
  const u16* Vg = &Vtg[(size_t)(bh * 64 + sr) * LK + sc];

  // prologue: tile 0 (one bf16x8 per thread for K and V)
  bf16x8 kr = *(const bf16x8*)(Kg);
  bf16x8 vr = *(const bf16x8*)(Vg);
  *(bf16x8*)&Ks[sr * 72 + sc] = kr;
  *(bf16x8*)&Vt[sr * 72 + sc] = vr;

  for (int t = 0; t < 16; ++t) {
    __syncthreads();   // staged LDS visible
    if (t < 15) {      // prefetch next tile into regs (hides HBM/L2 latency)
      const int k1 = (t + 1) * 64;
      kr = *(const bf16x8*)(Kg + (size_t)k1 * E_DIM);
      vr = *(const bf16x8*)(Vg + k1);
    }
    // S^T = K Q^T ; lane holds S^T[k=kf*16+lg*4+i][q=lr]
#pragma unroll
    for (int kf = 0; kf < 4; ++kf) {
      const bf16x8 kb0 = *(const bf16x8*)&Ks[(kf * 16 + lr) * 72 + lg * 8];
      const bf16x8 kb1 = *(const bf16x8*)&Ks[(kf * 16 + lr) * 72 + 32 + lg * 8];
      f32x4 s = fzero;
      s = MFMA_BF16(kb0, qf0, s);
      s = MFMA_BF16(kb1, qf1, s);
      const float p0 = exp2f(s[0]), p1 = exp2f(s[1]);
      const float p2 = exp2f(s[2]), p3 = exp2f(s[3]);
      dnl += (p0 + p1) + (p2 + p3);          // f32 denom, per-lane partial (q=lr)
      u32x2 w;
      w[0] = pack2bf(p0, p1);                // truncating bf16 pack, 1 v_perm per pair
      w[1] = pack2bf(p2, p3);
      *(u32x2_ma*)&Pw[wave][lr * 72 + kf * 16 + lg * 4] = w;   // k-contiguous 8B store
    }
    // PV: Pw same-wave write->read, DS in-order per wave -> no barrier needed
    const bf16x8 pa0 = *(const bf16x8_ma*)&Pw[wave][lr * 72 + lg * 8];
    const bf16x8 pa1 = *(const bf16x8_ma*)&Pw[wave][lr * 72 + 32 + lg * 8];
#pragma unroll
    for (int df = 0; df < 4; ++df) {
      const bf16x8 vb0 = *(const bf16x8*)&Vt[(df * 16 + lr) * 72 + lg * 8];
      const bf16x8 vb1 = *(const bf16x8*)&Vt[(df * 16 + lr) * 72 + 32 + lg * 8];
      ctx[df] = MFMA_BF16(pa0, vb0, ctx[df]);
      ctx[df] = MFMA_BF16(pa1, vb1, ctx[df]);
    }
    __syncthreads();   // all reads of Ks/Vt done
    if (t < 15) {
      *(bf16x8*)&Ks[sr * 72 + sc] = kr;
      *(bf16x8*)&Vt[sr * 72 + sc] = vr;
    }
  }

  // full denom per q=lr: sum over lg groups
  dnl += __shfl_xor(dnl, 16, 64);
  dnl += __shfl_xor(dnl, 32, 64);
  if (lane < 16) rden[(size_t)bh * LQ + q0 + wave * 16 + lane] = 0.0625f / dnl;
  float dnv[4];
#pragma unroll
  for (int i = 0; i < 4; ++i) dnv[i] = __shfl(dnl, lg * 4 + i, 64);

#pragma unroll
  for (int i = 0; i < 4; ++i) {
    const float inv = 1.0f / dnv[i];
    const int q = q0 + wave * 16 + lg * 4 + i;
    const size_t orow = (size_t)(b * LQ + q) * E_DIM + h * 64;
#pragma unroll
    for (int df = 0; df < 4; ++df)
      attnb[orow + df * 16 + lr] = f2bf(ctx[df][i] * inv);
  }
}

// ---------------------------------------------------------------- attn_weights = mean_h probs
// Block = (b, q-tile 128, k-chunk 128), 4 waves (2q x 2k quadrants of 64x64).
// Q and K staged in LDS (plain pad-72); K double-buffered, Q single-buffered.
// rden = 0.0625/denom precomputed by attn_fwd.
__global__ __launch_bounds__(256, 2) void attn_wts(
    const u16* __restrict__ Qb, const u16* __restrict__ Kb,
    const float* __restrict__ rden, float* __restrict__ aw) {
  __shared__ u16 Ks2[2][128 * 72];   // 36864 B
  __shared__ u16 Qs[128 * 72];       // 18432 B  (total 55296 B -> 2 blocks/CU)

  const int tid = threadIdx.x;
  const int wave = tid >> 6, lane = tid & 63;
  const int lr = lane & 15, lg = lane >> 4;
  const int wq = wave >> 1, wk = wave & 1;

  // XCD swizzle: 512 blocks, 64/XCD = one full b (8 q-tiles x 8 k-chunks)
  const int bid = blockIdx.x;
  const int wg = (bid & 7) * 64 + (bid >> 3);
  const int q0 = (wg & 7) * 128;
  const int k0 = ((wg >> 3) & 7) * 128;
  const int b = wg >> 6;

  const f32x4 fzero = {0.f, 0.f, 0.f, 0.f};
  f32x4 acc[4][4];   // [ksub t][qsub j]
#pragma unroll
  for (int t = 0; t < 4; ++t)
#pragma unroll
    for (int j = 0; j < 4; ++j) acc[t][j] = fzero;

  const int sr = tid >> 1;          // 0..127
  const int sc = (tid & 1) * 32;    // 0 / 32
  const u16* Kg = &Kb[(size_t)(b * LK + k0 + sr) * E_DIM + sc];
  const u16* Qg = &Qb[(size_t)(b * LQ + q0 + sr) * E_DIM + sc];
  const float* dg = &rden[(size_t)(b * H_NUM) * LQ + q0 + wq * 64 + lr];

  bf16x8 kr[4], qr[4];
  // prologue: h=0 K into buf0, Q(0) into regs (written at loop top)
#pragma unroll
  for (int c = 0; c < 4; ++c) kr[c] = *(const bf16x8*)(Kg + c * 8);
#pragma unroll
  for (int c = 0; c < 4; ++c) qr[c] = *(const bf16x8*)(Qg + c * 8);
#pragma unroll
  for (int c = 0; c < 4; ++c) *(bf16x8*)&Ks2[0][sr * 72 + sc + c * 8] = kr[c];

  for (int h = 0; h < H_NUM; ++h) {
    __syncthreads();   // (A) prev Qs reads done everywhere; Ks2[h&1] writes visible
    // write this head's Q (prefetched last iter / prologue)
#pragma unroll
    for (int c = 0; c < 4; ++c) *(bf16x8*)&Qs[sr * 72 + sc + c * 8] = qr[c];
    __syncthreads();   // (B) Qs(h) visible

    // issue next head's K/Q prefetch AFTER the barrier -> in flight across compute
    if (h < 15) {
#pragma unroll
      for (int c = 0; c < 4; ++c) kr[c] = *(const bf16x8*)(Kg + (h + 1) * 64 + c * 8);
#pragma unroll
      for (int c = 0; c < 4; ++c) qr[c] = *(const bf16x8*)(Qg + (h + 1) * 64 + c * 8);
    }
    float rd[4];
#pragma unroll
    for (int j = 0; j < 4; ++j) rd[j] = dg[(size_t)h * LQ + j * 16];

    // K-frags for all 4 k-subtiles in regs (8 x b128 LDS reads)
    const u16* Kbuf = &Ks2[h & 1][0];
    bf16x8 kb[4][2];
#pragma unroll
    for (int t = 0; t < 4; ++t) {
      const int row = wk * 64 + t * 16 + lr;
      kb[t][0] = *(const bf16x8*)&Kbuf[row * 72 + lg * 8];
      kb[t][1] = *(const bf16x8*)&Kbuf[row * 72 + 32 + lg * 8];
    }
#pragma unroll
    for (int j = 0; j < 4; ++j) {
      const int qrow = wq * 64 + j * 16 + lr;
      const bf16x8 qf0 = *(const bf16x8*)&Qs[qrow * 72 + lg * 8];
      const bf16x8 qf1 = *(const bf16x8*)&Qs[qrow * 72 + 32 + lg * 8];
#pragma unroll
      for (int t = 0; t < 4; ++t) {
        f32x4 s = fzero;
        s = MFMA_BF16(kb[t][0], qf0, s);   // D[k=lg*4+i][q=lr]
        s = MFMA_BF16(kb[t][1], qf1, s);
#pragma unroll
        for (int i = 0; i < 4; ++i)
          acc[t][j][i] += exp2f(s[i]) * rd[j];
      }
    }

    // write next head's K to the opposite buffer (waits on kr arrival; hidden by compute)
    if (h < 15) {
      u16* Kw = &Ks2[(h + 1) & 1][0];
#pragma unroll
      for (int c = 0; c < 4; ++c) *(bf16x8*)&Kw[sr * 72 + sc + c * 8] = kr[c];
    }
  }

  // store: k-contiguous f32x4 per (ksub, qsub)
#pragma unroll
  for (int j = 0; j < 4; ++j) {
    const size_t orow = (size_t)(b * LQ + q0 + wq * 64 + j * 16 + lr) * LK;
#pragma unroll
    for (int t = 0; t < 4; ++t)
      *(f32x4_ma*)&aw[orow + k0 + wk * 64 + t * 16 + lg * 4] = acc[t][j];
  }
}

// ---------------------------------------------------------------- LayerNorm (in place)
__global__ __launch_bounds__(256) void ln_kernel(float* __restrict__ xy,
                                                 const float* __restrict__ gamma,
                                                 const float* __restrict__ beta) {
  __shared__ float ls[4], ls2[4];
  const int row = blockIdx.x;
  const int tid = threadIdx.x;
  float4* xr = (float4*)(xy + (size_t)row * E_DIM);
  float4 v = xr[tid];
  float s = v.x + v.y + v.z + v.w;
  float s2 = v.x * v.x + v.y * v.y + v.z * v.z + v.w * v.w;
#pragma unroll
  for (int off = 32; off >= 1; off >>= 1) {
    s += __shfl_xor(s, off, 64);
    s2 += __shfl_xor(s2, off, 64);
  }
  const int wave = tid >> 6, lane = tid & 63;
  if (lane == 0) { ls[wave] = s; ls2[wave] = s2; }
  __syncthreads();
  s = ls[0] + ls[1] + ls[2] + ls[3];
  s2 = ls2[0] + ls2[1] + ls2[2] + ls2[3];
  const float mu = s * (1.0f / E_DIM);
  const float var = s2 * (1.0f / E_DIM) - mu * mu;
  const float rs = rsqrtf(var + 1e-5f);
  const float4 g = ((const float4*)gamma)[tid];
  const float4 bt = ((const float4*)beta)[tid];
  float4 o;
  o.x = (v.x - mu) * rs * g.x + bt.x;
  o.y = (v.y - mu) * rs * g.y + bt.y;
  o.z = (v.z - mu) * rs * g.z + bt.z;
  o.w = (v.w - mu) * rs * g.w + bt.w;
  xr[tid] = o;
}

// ---------------------------------------------------------------- launch
extern "C" void kernel_launch(void* const* d_in, const int* in_sizes, int n_in,
                              void* d_out, int out_size, void* d_ws, size_t ws_size,
                              hipStream_t stream) {
  (void)in_sizes; (void)n_in; (void)out_size; (void)ws_size;
  const float* query     = (const float*)d_in[0];
  const float* key_t     = (const float*)d_in[1];
  const float* value     = (const float*)d_in[2];
  const float* in_proj_b = (const float*)d_in[4];
  const float* out_proj_b = (const float*)d_in[6];
  const float* ln_gamma  = (const float*)d_in[7];
  const float* ln_beta   = (const float*)d_in[8];

  float* y  = (float*)d_out;                       // (B,Lq,E) f32
  float* aw = y + (size_t)B_NUM * LQ * E_DIM;      // (B,Lq,Lk) f32

  const size_t SZ = (size_t)B_NUM * LQ * E_DIM;    // 8388608
  u16* ws    = (u16*)d_ws;
  u16* Qb    = ws;                 // bf16, 0.125*log2e folded
  u16* Kb    = ws + SZ;
  u16* Vb    = ws + 2 * SZ;
  u16* attnb = ws + 3 * SZ;
  u16* wqkvb = ws + 4 * SZ;                        // 3*E*E bf16
  u16* woutb = wqkvb + 3 * E_DIM * E_DIM;          // E*E bf16
  float* rden = (float*)(wqkvb + 4 * (size_t)E_DIM * E_DIM);   // B*H*Lq f32

  // d_out scratch reuse (all stream-ordered):
  //   aw region: Xq,Xk (bf16 inputs) until gemm0 done; attn_wts writes aw later.
  //   y  region: Xv until gemm0 done; then Vtg until attn_fwd done; gemm128_out writes y after.
  u16* Xq  = (u16*)aw;
  u16* Xk  = Xq + SZ;
  u16* Xv  = (u16*)y;
  u16* Vtg = (u16*)y;

  cvt_f32_bf16<<<3072, 256, 0, stream>>>((const float*)d_in[3], wqkvb, (3 * E_DIM * E_DIM) / 4);
  cvt_f32_bf16<<<1024, 256, 0, stream>>>((const float*)d_in[5], woutb, (E_DIM * E_DIM) / 4);
  cvt3_f32_bf16<<<dim3(2048, 3), 256, 0, stream>>>(query, key_t, value, Xq, Xk, Xv, (int)(SZ / 4));

  // QKV projection: 32 m-tiles x 4 n-tiles x 3 z = 384 blocks (%8==0); BK=32 db, 2 blocks/CU
  gemm_qkv<<<384, 512, 0, stream>>>(
      Xq, Xk, Xv, wqkvb, in_proj_b, Qb, 4, 32);

  transpose_v<<<dim3(4, 16, 8), 256, 0, stream>>>(Vb, Vtg);

  // attn_fwd: 8 qt(128) x 16 h x 8 b = 1024 blocks, 512 threads
  attn_fwd<<<1024, 512, 0, stream>>>(Qb, Kb, Vtg, attnb, rden);

  // aw: 8 b x 8 q-tiles(128) x 8 k-chunks(128) = 512 blocks
  attn_wts<<<512, 256, 0, stream>>>(Qb, Kb, rden, aw);

  // out-proj + bias + residual: 64 m x 8 n = 512 blocks (full machine)
  gemm128_out<<<512, 256, 0, stream>>>(attnb, woutb, out_proj_b, query, y, 8, 64);

  ln_kernel<<<8192, 256, 0, stream>>>(y, ln_gamma, ln_beta);
}

// Round 14
// 255.806 us; speedup vs baseline: 2.6225x; 2.6225x over previous
//
#include <hip/hip_runtime.h>
#include <stdint.h>

#define E_DIM 1024
#define H_NUM 16
#define B_NUM 8
#define LQ 1024
#define LK 1024
#define MROWS (B_NUM * LQ)   // 8192

typedef unsigned short u16;
typedef __attribute__((ext_vector_type(8))) short bf16x8;
typedef __attribute__((ext_vector_type(4))) short bf16x4;
typedef __attribute__((ext_vector_type(4))) float f32x4;
typedef __attribute__((ext_vector_type(2))) unsigned int u32x2;
typedef bf16x8 __attribute__((may_alias)) bf16x8_ma;
typedef bf16x4 __attribute__((may_alias)) bf16x4_ma;
typedef f32x4 __attribute__((may_alias)) f32x4_ma;
typedef u32x2 __attribute__((may_alias)) u32x2_ma;

typedef __attribute__((address_space(1))) const void* gas_ptr;
typedef __attribute__((address_space(3))) void* las_ptr;

__device__ __forceinline__ void gload16(const void* g, void* l) {
  __builtin_amdgcn_global_load_lds((gas_ptr)g, (las_ptr)l, 16, 0, 0);
}

__device__ __forceinline__ u16 f2bf(float f) {
  union { float f; uint32_t u; } c; c.f = f;
  return (u16)((c.u + 0x7FFFu + ((c.u >> 16) & 1u)) >> 16);
}

// pack two f32 -> two bf16 (truncation) in one v_perm
__device__ __forceinline__ uint32_t pack2bf(float lo, float hi) {
  return __builtin_amdgcn_perm(__float_as_uint(hi), __float_as_uint(lo), 0x07060302u);
}

#define MFMA_BF16(a, b, c) __builtin_amdgcn_mfma_f32_16x16x32_bf16((a), (b), (c), 0, 0, 0)

// Q scale: 1/sqrt(64) * log2(e), folded into Qb so attn kernels use exp2 directly
#define SCALE_Q 0.18033688011112042f

// SESSION NOTES (post-mortems):
//  R8:  no XOR swizzles on pad-72 attn LDS tiles (pad-72 already bank-minimal).
//  R11: BK=32 ring-4 @128K LDS regressed (more barriers, no residency gain).
//  R12: barrier-halving at 1 block/CU null -> intra-block schedule not the lever.
//  R13: launch_bounds(512,4) with a 128-reg accumulator forces scratch spills
//       (1.77 GB HBM traffic). 256^2 tile => ~250 regs/wave => 2 waves/SIMD
//       => 1 block/CU at 512 thr is STRUCTURAL. gemm0 plateau ~613 TF at K=1024.

// ---------------------------------------------------------------- fused cvt f32->bf16 (5 buffers)
__global__ __launch_bounds__(256) void cvt_all(
    const float* __restrict__ s0, const float* __restrict__ s1,
    const float* __restrict__ s2, const float* __restrict__ s3,
    const float* __restrict__ s4,
    u16* __restrict__ d0, u16* __restrict__ d1, u16* __restrict__ d2,
    u16* __restrict__ d3, u16* __restrict__ d4,
    int c0, int c1, int c2) {
  const int y = blockIdx.y;
  const float* s = (y == 0) ? s0 : (y == 1) ? s1 : (y == 2) ? s2 : (y == 3) ? s3 : s4;
  u16* d = (y == 0) ? d0 : (y == 1) ? d1 : (y == 2) ? d2 : (y == 3) ? d3 : d4;
  const int n4 = (y == 0) ? c0 : (y == 1) ? c1 : c2;
  const int stride = gridDim.x * 256;
  for (int i = blockIdx.x * 256 + threadIdx.x; i < n4; i += stride) {
    float4 v = ((const float4*)s)[i];
    ushort4 o;
    o.x = f2bf(v.x); o.y = f2bf(v.y); o.z = f2bf(v.z); o.w = f2bf(v.w);
    ((ushort4*)d)[i] = o;
  }
}

// ---------------------------------------------------------------- QKV GEMM: 256x256 8-phase
// (R10-proven: 128 KiB LDS double-buffer, counted vmcnt(6), st_16x32 swizzle, setprio)

#define BAR() __builtin_amdgcn_s_barrier()
#define LGKM0() do { asm volatile("s_waitcnt lgkmcnt(0)" ::: "memory"); \
                     __builtin_amdgcn_sched_barrier(0); } while (0)
#define LGKM8() asm volatile("s_waitcnt lgkmcnt(8)" ::: "memory")
#define VMC(n) asm volatile("s_waitcnt vmcnt(" n ")" ::: "memory")

#define STAGEH(mat, rowbase, kt, ldsoff)                                     \
  { const u16* _s = (mat) + (size_t)(rowbase) * E_DIM + (kt);                \
    gload16(_s + goff0, ldsv + (ldsoff) + wave * 1024);                      \
    gload16(_s + goff1, ldsv + (ldsoff) + 8192 + wave * 1024); }

#define READ_B(db)                                                           \
  _Pragma("unroll") for (int n = 0; n < 4; ++n) {                            \
    const int rgb = wn4 + n;                                                 \
    _Pragma("unroll") for (int ks = 0; ks < 2; ++ks)                         \
      bfr[n][ks] = *(const bf16x8_ma*)(ldsc + 65536 + (db) * 32768 +         \
          ((rgb >> 3) << 14) + (((rgb & 7) * 2 + ks) << 10) + lanebase);     \
  }

#define READ_A(db, q)                                                        \
  _Pragma("unroll") for (int jj = 0; jj < 2; ++jj) {                         \
    const int rga = 4 * (q) + 2 * jj + wm;                                   \
    _Pragma("unroll") for (int ks = 0; ks < 2; ++ks)                         \
      afr[jj][ks] = *(const bf16x8_ma*)(ldsc + (db) * 32768 +                \
          ((rga >> 3) << 14) + (((rga & 7) * 2 + ks) << 10) + lanebase);     \
  }

#define MMA(q)                                                               \
  __builtin_amdgcn_s_setprio(1);                                             \
  _Pragma("unroll") for (int jj = 0; jj < 2; ++jj)                           \
    _Pragma("unroll") for (int n = 0; n < 4; ++n)                            \
      _Pragma("unroll") for (int ks = 0; ks < 2; ++ks)                       \
        acc[2 * (q) + jj][n] =                                               \
            MFMA_BF16(afr[jj][ks], bfr[n][ks], acc[2 * (q) + jj][n]);        \
  __builtin_amdgcn_s_setprio(0);

__global__ __launch_bounds__(512, 2) void gemm_qkv(
    const u16* __restrict__ A0, const u16* __restrict__ A1, const u16* __restrict__ A2,
    const u16* __restrict__ W, const float* __restrict__ bias,
    u16* __restrict__ outb, int nwg_n, int nwg_m) {
  __shared__ u16 lds[65536];  // bytes: A db0 | A db1 | B db0 | B db1 (32 KiB each)

  const int tid = threadIdx.x;
  const int wave = tid >> 6, lane = tid & 63;
  const int lr = lane & 15, lg = lane >> 4;
  const int wm = wave >> 2, wn4 = (wave & 3) * 4;

  // XCD swizzle (grid % 8 == 0); n-fastest so A-panels stay XCD-local
  const int cpx = (int)gridDim.x >> 3;
  const int bid = blockIdx.x;
  const int wg = (bid & 7) * cpx + (bid >> 3);
  const int n_i = wg % nwg_n;
  const int rest = wg / nwg_n;
  const int m_i = rest % nwg_m;
  const int z = rest / nwg_m;
  const int m0 = m_i * 256, n0 = n_i * 256;

  const u16* Az = (z == 0) ? A0 : (z == 1 ? A1 : A2);
  const u16* Wz = W + (size_t)z * E_DIM * E_DIM;
  const float* bs = bias + z * E_DIM;
  const float scale = (z == 0) ? SCALE_Q : 1.0f;

  // staging: per-thread inverse-swizzled GLOBAL source offsets (elements)
  int goff0, goff1;
  {
    const int X0 = wave * 1024 + lane * 16;
    const int L0 = X0 ^ (((X0 >> 9) & 1) << 5);
    goff0 = (((L0 >> 10) >> 1) * 16 + ((L0 >> 6) & 15)) * E_DIM +
            ((L0 >> 10) & 1) * 32 + ((L0 & 63) >> 1);
    const int X1 = 8192 + X0;
    const int L1 = X1 ^ (((X1 >> 9) & 1) << 5);
    goff1 = (((L1 >> 10) >> 1) * 16 + ((L1 >> 6) & 15)) * E_DIM +
            ((L1 >> 10) & 1) * 32 + ((L1 & 63) >> 1);
  }
  const char* ldsc = (const char*)lds;
  char* ldsv = (char*)lds;
  const int lanebase = lr * 64 + ((lg * 16) ^ ((lane & 8) << 2));

  const f32x4 fzero = {0.f, 0.f, 0.f, 0.f};
  f32x4 acc[8][4];
#pragma unroll
  for (int j = 0; j < 8; ++j)
#pragma unroll
    for (int n = 0; n < 4; ++n) acc[j][n] = fzero;

  // ---- prologue: tile0 fully (buf0), tile1 B0,B1,A0 (buf1). vmcnt(6) certifies tile0.
  STAGEH(Az, m0,       0,  0);              // t0.A0
  STAGEH(Az, m0 + 128, 0,  16384);          // t0.A1
  STAGEH(Wz, n0,       0,  65536);          // t0.B0
  STAGEH(Wz, n0 + 128, 0,  65536 + 16384);  // t0.B1
  STAGEH(Wz, n0,       64, 65536 + 32768);          // t1.B0
  STAGEH(Wz, n0 + 128, 64, 65536 + 32768 + 16384);  // t1.B1
  STAGEH(Az, m0,       64, 32768);          // t1.A0
  VMC("6");
  BAR();

  bf16x8 bfr[4][2], afr[2][2];
#pragma unroll 1
  for (int i = 0; i < 8; ++i) {
    const int kt2 = i * 128 + 128;  // k-offset of tile t0+2
    const bool nl = (i < 7);
    // q0: tile 2i, phase 0 (reads all B + A rows 0-63 of buf0)
    READ_B(0) READ_A(0, 0)
    STAGEH(Az, m0 + 128, i * 128 + 64, 32768 + 16384);  // t1.A1 (always, incl. i=7)
    LGKM8();
    BAR(); LGKM0();
    MMA(0)
    BAR();
    // q1
    READ_A(0, 1)
    if (nl) STAGEH(Wz, n0, kt2, 65536);                 // (t0+2).B0
    BAR(); LGKM0();
    MMA(1)
    BAR();
    // q2
    READ_A(0, 2)
    if (nl) STAGEH(Az, m0, kt2, 0);                     // (t0+2).A0
    BAR(); LGKM0();
    MMA(2)
    BAR();
    // q3  (vmcnt: certify tile 2i+1 before q4 reads it)
    READ_A(0, 3)
    if (nl) {
      STAGEH(Wz, n0 + 128, kt2, 65536 + 16384);         // (t0+2).B1
      VMC("6");
    } else {
      VMC("0");
    }
    BAR(); LGKM0();
    MMA(3)
    BAR();
    // q4: tile 2i+1, phase 0
    READ_B(1) READ_A(1, 0)
    if (nl) STAGEH(Az, m0 + 128, kt2, 16384);           // (t0+2).A1
    LGKM8();
    BAR(); LGKM0();
    MMA(0)
    BAR();
    // q5
    READ_A(1, 1)
    if (nl) STAGEH(Wz, n0, kt2 + 64, 65536 + 32768);    // (t1+2).B0
    BAR(); LGKM0();
    MMA(1)
    BAR();
    // q6
    READ_A(1, 2)
    if (nl) STAGEH(Wz, n0 + 128, kt2 + 64, 65536 + 32768 + 16384);  // (t1+2).B1
    BAR(); LGKM0();
    MMA(2)
    BAR();
    // q7  (vmcnt: certify tile 2i+2 before next-iter q0 reads it)
    READ_A(1, 3)
    if (nl) {
      STAGEH(Az, m0, kt2 + 64, 32768);                  // (t1+2).A0
      VMC("6");
    }
    BAR(); LGKM0();
    MMA(3)
    BAR();
  }

  float bvv[4];
#pragma unroll
  for (int n = 0; n < 4; ++n) bvv[n] = bs[n0 + wn4 * 16 + n * 16 + lr];

  u16* Cb = outb + (size_t)z * (size_t)MROWS * E_DIM;
#pragma unroll
  for (int j = 0; j < 8; ++j) {
    const int rbase = m0 + (2 * j + wm) * 16 + lg * 4;
#pragma unroll
    for (int ii = 0; ii < 4; ++ii) {
      const size_t m = (size_t)(rbase + ii);
#pragma unroll
      for (int n = 0; n < 4; ++n) {
        const int nn = n0 + wn4 * 16 + n * 16 + lr;
        Cb[m * E_DIM + nn] = f2bf((acc[j][n][ii] + bvv[n]) * scale);
      }
    }
  }
}

// ---------------------------------------------------------------- 128x128 2-phase GEMM (out-proj)
// C = A @ W^T + bias + resid (f32 out). 512 blocks -> full machine (~520 TF structure).
__global__ __launch_bounds__(256) void gemm128_out(
    const u16* __restrict__ A, const u16* __restrict__ W,
    const float* __restrict__ bias, const float* __restrict__ resid,
    float* __restrict__ outf, int nwg_n, int nwg_m) {
  __shared__ u16 As[128 * 64];
  __shared__ u16 Bs[128 * 64];

  const int tid = threadIdx.x;
  const int wave = tid >> 6;
  const int lane = tid & 63;
  const int lr = lane & 15, lg = lane >> 4;
  const int wr = wave >> 1, wc = wave & 1;

  const int cpx = (int)gridDim.x >> 3;
  const int bid = blockIdx.x;
  const int wg = (bid & 7) * cpx + (bid >> 3);
  const int n_i = wg % nwg_n;
  const int m_i = (wg / nwg_n) % nwg_m;

  const int m0 = m_i * 128;
  const int n0 = n_i * 128;

  const f32x4 fzero = {0.f, 0.f, 0.f, 0.f};
  f32x4 acc[4][4];
#pragma unroll
  for (int a = 0; a < 4; ++a)
#pragma unroll
    for (int b = 0; b < 4; ++b) acc[a][b] = fzero;

  const int lrow8 = lane >> 3;        // 0..7
  const int lcol8 = (lane & 7) * 8;   // 0..56

  for (int kt = 0; kt < E_DIM; kt += 64) {
#pragma unroll
    for (int i = 0; i < 4; ++i) {
      const int seg = i * 4 + wave;   // 0..15, each covers 1024 B (8 rows)
      gload16(W + (size_t)(n0 + seg * 8 + lrow8) * E_DIM + kt + lcol8, &Bs[seg * 512]);
      gload16(A + (size_t)(m0 + seg * 8 + lrow8) * E_DIM + kt + lcol8, &As[seg * 512]);
    }
    __syncthreads();

#pragma unroll
    for (int kk = 0; kk < 64; kk += 32) {
      bf16x8 av[4], bv[4];
#pragma unroll
      for (int t = 0; t < 4; ++t)
        av[t] = *(const bf16x8*)&As[(wr * 64 + t * 16 + lr) * 64 + kk + lg * 8];
#pragma unroll
      for (int t = 0; t < 4; ++t)
        bv[t] = *(const bf16x8*)&Bs[(wc * 64 + t * 16 + lr) * 64 + kk + lg * 8];
#pragma unroll
      for (int mi = 0; mi < 4; ++mi)
#pragma unroll
        for (int ni = 0; ni < 4; ++ni)
          acc[mi][ni] = MFMA_BF16(av[mi], bv[ni], acc[mi][ni]);
    }
    __syncthreads();
  }

  float bvv[4];
#pragma unroll
  for (int ni = 0; ni < 4; ++ni) bvv[ni] = bias[n0 + wc * 64 + ni * 16 + lr];

#pragma unroll
  for (int mi = 0; mi < 4; ++mi) {
#pragma unroll
    for (int i = 0; i < 4; ++i) {
      const size_t m = (size_t)(m0 + wr * 64 + mi * 16 + lg * 4 + i);
#pragma unroll
      for (int ni = 0; ni < 4; ++ni) {
        const int n = n0 + wc * 64 + ni * 16 + lr;
        outf[m * E_DIM + n] = acc[mi][ni][i] + bvv[ni] + resid[m * E_DIM + n];
      }
    }
  }
}

// ---------------------------------------------------------------- V transpose (once)
// Vb (b,k,h*64+d) -> Vtg[(b*16+h)*64 + d][k]
__global__ __launch_bounds__(256) void transpose_v(const u16* __restrict__ Vb,
                                                   u16* __restrict__ Vtg) {
  __shared__ u16 T[64 * 264];
  const int tid = threadIdx.x;
  const int b = blockIdx.z, h = blockIdx.y;
  const int k0 = blockIdx.x * 256;
  const int bh = b * H_NUM + h;
  const int krow = tid >> 3;          // 0..31
  const int d0 = (tid & 7) * 8;
  const int jst = krow & 7;           // stagger to spread banks
#pragma unroll
  for (int it = 0; it < 8; ++it) {
    const int k = it * 32 + krow;
    bf16x8 v = *(const bf16x8*)&Vb[(size_t)(b * LK + k0 + k) * E_DIM + h * 64 + d0];
#pragma unroll
    for (int jj = 0; jj < 8; ++jj) {
      const int j = (jj + jst) & 7;
      T[(d0 + j) * 264 + k] = (u16)v[j];
    }
  }
  __syncthreads();
  const int d = tid >> 2;
  const int kk0 = (tid & 3) * 64;
  u16* orow = &Vtg[(size_t)(bh * 64 + d) * LK + k0 + kk0];
#pragma unroll
  for (int c = 0; c < 8; ++c)
    *(bf16x8*)&orow[c * 8] = *(const bf16x8*)&T[d * 264 + kk0 + c * 8];
}

// ---------------------------------------------------------------- attention fwd (swapped QK^T)
// per (b, h, 128-row q-tile); 8 waves x 16 q-rows each. |S|<~5 -> no max subtraction.
// Plain pad-72 LDS; pack2bf truncation for P. Stores rden = 0.0625/denom.
__global__ __launch_bounds__(512) void attn_fwd(
    const u16* __restrict__ Qb, const u16* __restrict__ Kb, const u16* __restrict__ Vtg,
    u16* __restrict__ attnb, float* __restrict__ rden) {
  __shared__ u16 Ks[64 * 72];
  __shared__ u16 Vt[64 * 72];
  __shared__ u16 Pw[8][16 * 72];

  const int tid = threadIdx.x;
  const int wave = tid >> 6, lane = tid & 63;
  const int lr = lane & 15, lg = lane >> 4;

  // XCD swizzle: 1024 blocks, 128/XCD = one full b; consecutive 8 blocks share (b,h)
  const int bid = blockIdx.x;
  const int wg = (bid & 7) * 128 + (bid >> 3);
  const int qt = wg & 7;
  const int h = (wg >> 3) & 15;
  const int b = wg >> 7;
  const int bh = b * H_NUM + h;
  const int q0 = qt * 128;

  const size_t qoff = (size_t)(b * LQ + q0 + wave * 16 + lr) * E_DIM + h * 64;
  const bf16x8 qf0 = *(const bf16x8*)&Qb[qoff + lg * 8];
  const bf16x8 qf1 = *(const bf16x8*)&Qb[qoff + 32 + lg * 8];

  const f32x4 fzero = {0.f, 0.f, 0.f, 0.f};
  f32x4 ctx[4];
#pragma unroll
  for (int d = 0; d < 4; ++d) ctx[d] = fzero;
  float dnl = 0.f;

  const int sr = tid >> 3;        // 0..63
  const int sc = (tid & 7) * 8;   // 0..56
  const u16* Kg = &Kb[(size_t)(b * LK + sr) * E_DIM + h * 64 + sc];
  const u16* Vg = &Vtg[(size_t)(bh * 64 + sr) * LK + sc];

  // prologue: tile 0 (one bf16x8 per thread for K and V)
  bf16x8 kr = *(const bf16x8*)(Kg);
  bf16x8 vr = *(const bf16x8*)(Vg);
  *(bf16x8*)&Ks[sr * 72 + sc] = kr;
  *(bf16x8*)&Vt[sr * 72 + sc] = vr;

  for (int t = 0; t < 16; ++t) {
    __syncthreads();   // staged LDS visible
    if (t < 15) {      // prefetch next tile into regs (hides HBM/L2 latency)
      const int k1 = (t + 1) * 64;
      kr = *(const bf16x8*)(Kg + (size_t)k1 * E_DIM);
      vr = *(const bf16x8*)(Vg + k1);
    }
    // S^T = K Q^T ; lane holds S^T[k=kf*16+lg*4+i][q=lr]
#pragma unroll
    for (int kf = 0; kf < 4; ++kf) {
      const bf16x8 kb0 = *(const bf16x8*)&Ks[(kf * 16 + lr) * 72 + lg * 8];
      const bf16x8 kb1 = *(const bf16x8*)&Ks[(kf * 16 + lr) * 72 + 32 + lg * 8];
      f32x4 s = fzero;
      s = MFMA_BF16(kb0, qf0, s);
      s = MFMA_BF16(kb1, qf1, s);
      const float p0 = exp2f(s[0]), p1 = exp2f(s[1]);
      const float p2 = exp2f(s[2]), p3 = exp2f(s[3]);
      dnl += (p0 + p1) + (p2 + p3);          // f32 denom, per-lane partial (q=lr)
      u32x2 w;
      w[0] = pack2bf(p0, p1);                // truncating bf16 pack, 1 v_perm per pair
      w[1] = pack2bf(p2, p3);
      *(u32x2_ma*)&Pw[wave][lr * 72 + kf * 16 + lg * 4] = w;   // k-contiguous 8B store
    }
    // PV: Pw same-wave write->read, DS in-order per wave -> no barrier needed
    const bf16x8 pa0 = *(const bf16x8_ma*)&Pw[wave][lr * 72 + lg * 8];
    const bf16x8 pa1 = *(const bf16x8_ma*)&Pw[wave][lr * 72 + 32 + lg * 8];
#pragma unroll
    for (int df = 0; df < 4; ++df) {
      const bf16x8 vb0 = *(const bf16x8*)&Vt[(df * 16 + lr) * 72 + lg * 8];
      const bf16x8 vb1 = *(const bf16x8*)&Vt[(df * 16 + lr) * 72 + 32 + lg * 8];
      ctx[df] = MFMA_BF16(pa0, vb0, ctx[df]);
      ctx[df] = MFMA_BF16(pa1, vb1, ctx[df]);
    }
    __syncthreads();   // all reads of Ks/Vt done
    if (t < 15) {
      *(bf16x8*)&Ks[sr * 72 + sc] = kr;
      *(bf16x8*)&Vt[sr * 72 + sc] = vr;
    }
  }

  // full denom per q=lr: sum over lg groups
  dnl += __shfl_xor(dnl, 16, 64);
  dnl += __shfl_xor(dnl, 32, 64);
  if (lane < 16) rden[(size_t)bh * LQ + q0 + wave * 16 + lane] = 0.0625f / dnl;
  float dnv[4];
#pragma unroll
  for (int i = 0; i < 4; ++i) dnv[i] = __shfl(dnl, lg * 4 + i, 64);

#pragma unroll
  for (int i = 0; i < 4; ++i) {
    const float inv = 1.0f / dnv[i];
    const int q = q0 + wave * 16 + lg * 4 + i;
    const size_t orow = (size_t)(b * LQ + q) * E_DIM + h * 64;
#pragma unroll
    for (int df = 0; df < 4; ++df)
      attnb[orow + df * 16 + lr] = f2bf(ctx[df][i] * inv);
  }
}

// ---------------------------------------------------------------- attn_weights = mean_h probs
// Block = (b, q-tile 128, k-chunk 128), 4 waves (2q x 2k quadrants of 64x64).
// Q and K staged in LDS (plain pad-72); K double-buffered, Q single-buffered.
// rden = 0.0625/denom precomputed by attn_fwd.
__global__ __launch_bounds__(256, 2) void attn_wts(
    const u16* __restrict__ Qb, const u16* __restrict__ Kb,
    const float* __restrict__ rden, float* __restrict__ aw) {
  __shared__ u16 Ks2[2][128 * 72];   // 36864 B
  __shared__ u16 Qs[128 * 72];       // 18432 B  (total 55296 B -> 2 blocks/CU)

  const int tid = threadIdx.x;
  const int wave = tid >> 6, lane = tid & 63;
  const int lr = lane & 15, lg = lane >> 4;
  const int wq = wave >> 1, wk = wave & 1;

  // XCD swizzle: 512 blocks, 64/XCD = one full b (8 q-tiles x 8 k-chunks)
  const int bid = blockIdx.x;
  const int wg = (bid & 7) * 64 + (bid >> 3);
  const int q0 = (wg & 7) * 128;
  const int k0 = ((wg >> 3) & 7) * 128;
  const int b = wg >> 6;

  const f32x4 fzero = {0.f, 0.f, 0.f, 0.f};
  f32x4 acc[4][4];   // [ksub t][qsub j]
#pragma unroll
  for (int t = 0; t < 4; ++t)
#pragma unroll
    for (int j = 0; j < 4; ++j) acc[t][j] = fzero;

  const int sr = tid >> 1;          // 0..127
  const int sc = (tid & 1) * 32;    // 0 / 32
  const u16* Kg = &Kb[(size_t)(b * LK + k0 + sr) * E_DIM + sc];
  const u16* Qg = &Qb[(size_t)(b * LQ + q0 + sr) * E_DIM + sc];
  const float* dg = &rden[(size_t)(b * H_NUM) * LQ + q0 + wq * 64 + lr];

  bf16x8 kr[4], qr[4];
  // prologue: h=0 K into buf0, Q(0) into regs (written at loop top)
#pragma unroll
  for (int c = 0; c < 4; ++c) kr[c] = *(const bf16x8*)(Kg + c * 8);
#pragma unroll
  for (int c = 0; c < 4; ++c) qr[c] = *(const bf16x8*)(Qg + c * 8);
#pragma unroll
  for (int c = 0; c < 4; ++c) *(bf16x8*)&Ks2[0][sr * 72 + sc + c * 8] = kr[c];

  for (int h = 0; h < H_NUM; ++h) {
    __syncthreads();   // (A) prev Qs reads done everywhere; Ks2[h&1] writes visible
    // write this head's Q (prefetched last iter / prologue)
#pragma unroll
    for (int c = 0; c < 4; ++c) *(bf16x8*)&Qs[sr * 72 + sc + c * 8] = qr[c];
    __syncthreads();   // (B) Qs(h) visible

    // issue next head's K/Q prefetch AFTER the barrier -> in flight across compute
    if (h < 15) {
#pragma unroll
      for (int c = 0; c < 4; ++c) kr[c] = *(const bf16x8*)(Kg + (h + 1) * 64 + c * 8);
#pragma unroll
      for (int c = 0; c < 4; ++c) qr[c] = *(const bf16x8*)(Qg + (h + 1) * 64 + c * 8);
    }
    float rd[4];
#pragma unroll
    for (int j = 0; j < 4; ++j) rd[j] = dg[(size_t)h * LQ + j * 16];

    // K-frags for all 4 k-subtiles in regs (8 x b128 LDS reads)
    const u16* Kbuf = &Ks2[h & 1][0];
    bf16x8 kb[4][2];
#pragma unroll
    for (int t = 0; t < 4; ++t) {
      const int row = wk * 64 + t * 16 + lr;
      kb[t][0] = *(const bf16x8*)&Kbuf[row * 72 + lg * 8];
      kb[t][1] = *(const bf16x8*)&Kbuf[row * 72 + 32 + lg * 8];
    }
#pragma unroll
    for (int j = 0; j < 4; ++j) {
      const int qrow = wq * 64 + j * 16 + lr;
      const bf16x8 qf0 = *(const bf16x8*)&Qs[qrow * 72 + lg * 8];
      const bf16x8 qf1 = *(const bf16x8*)&Qs[qrow * 72 + 32 + lg * 8];
#pragma unroll
      for (int t = 0; t < 4; ++t) {
        f32x4 s = fzero;
        s = MFMA_BF16(kb[t][0], qf0, s);   // D[k=lg*4+i][q=lr]
        s = MFMA_BF16(kb[t][1], qf1, s);
#pragma unroll
        for (int i = 0; i < 4; ++i)
          acc[t][j][i] += exp2f(s[i]) * rd[j];
      }
    }

    // write next head's K to the opposite buffer (waits on kr arrival; hidden by compute)
    if (h < 15) {
      u16* Kw = &Ks2[(h + 1) & 1][0];
#pragma unroll
      for (int c = 0; c < 4; ++c) *(bf16x8*)&Kw[sr * 72 + sc + c * 8] = kr[c];
    }
  }

  // store: k-contiguous f32x4 per (ksub, qsub)
#pragma unroll
  for (int j = 0; j < 4; ++j) {
    const size_t orow = (size_t)(b * LQ + q0 + wq * 64 + j * 16 + lr) * LK;
#pragma unroll
    for (int t = 0; t < 4; ++t)
      *(f32x4_ma*)&aw[orow + k0 + wk * 64 + t * 16 + lg * 4] = acc[t][j];
  }
}

// ---------------------------------------------------------------- LayerNorm (in place)
__global__ __launch_bounds__(256) void ln_kernel(float* __restrict__ xy,
                                                 const float* __restrict__ gamma,
                                                 const float* __restrict__ beta) {
  __shared__ float ls[4], ls2[4];
  const int row = blockIdx.x;
  const int tid = threadIdx.x;
  float4* xr = (float4*)(xy + (size_t)row * E_DIM);
  float4 v = xr[tid];
  float s = v.x + v.y + v.z + v.w;
  float s2 = v.x * v.x + v.y * v.y + v.z * v.z + v.w * v.w;
#pragma unroll
  for (int off = 32; off >= 1; off >>= 1) {
    s += __shfl_xor(s, off, 64);
    s2 += __shfl_xor(s2, off, 64);
  }
  const int wave = tid >> 6, lane = tid & 63;
  if (lane == 0) { ls[wave] = s; ls2[wave] = s2; }
  __syncthreads();
  s = ls[0] + ls[1] + ls[2] + ls[3];
  s2 = ls2[0] + ls2[1] + ls2[2] + ls2[3];
  const float mu = s * (1.0f / E_DIM);
  const float var = s2 * (1.0f / E_DIM) - mu * mu;
  const float rs = rsqrtf(var + 1e-5f);
  const float4 g = ((const float4*)gamma)[tid];
  const float4 bt = ((const float4*)beta)[tid];
  float4 o;
  o.x = (v.x - mu) * rs * g.x + bt.x;
  o.y = (v.y - mu) * rs * g.y + bt.y;
  o.z = (v.z - mu) * rs * g.z + bt.z;
  o.w = (v.w - mu) * rs * g.w + bt.w;
  xr[tid] = o;
}

// ---------------------------------------------------------------- launch
extern "C" void kernel_launch(void* const* d_in, const int* in_sizes, int n_in,
                              void* d_out, int out_size, void* d_ws, size_t ws_size,
                              hipStream_t stream) {
  (void)in_sizes; (void)n_in; (void)out_size; (void)ws_size;
  const float* query     = (const float*)d_in[0];
  const float* key_t     = (const float*)d_in[1];
  const float* value     = (const float*)d_in[2];
  const float* in_proj_w = (const float*)d_in[3];
  const float* in_proj_b = (const float*)d_in[4];
  const float* out_proj_w = (const float*)d_in[5];
  const float* out_proj_b = (const float*)d_in[6];
  const float* ln_gamma  = (const float*)d_in[7];
  const float* ln_beta   = (const float*)d_in[8];

  float* y  = (float*)d_out;                       // (B,Lq,E) f32
  float* aw = y + (size_t)B_NUM * LQ * E_DIM;      // (B,Lq,Lk) f32

  const size_t SZ = (size_t)B_NUM * LQ * E_DIM;    // 8388608
  u16* ws    = (u16*)d_ws;
  u16* Qb    = ws;                 // bf16, 0.125*log2e folded
  u16* Kb    = ws + SZ;
  u16* Vb    = ws + 2 * SZ;
  u16* attnb = ws + 3 * SZ;
  u16* wqkvb = ws + 4 * SZ;                        // 3*E*E bf16
  u16* woutb = wqkvb + 3 * E_DIM * E_DIM;          // E*E bf16
  float* rden = (float*)(wqkvb + 4 * (size_t)E_DIM * E_DIM);   // B*H*Lq f32

  // d_out scratch reuse (all stream-ordered):
  //   aw region: Xq,Xk (bf16 inputs) until gemm0 done; attn_wts writes aw later.
  //   y  region: Xv until gemm0 done; then Vtg until attn_fwd done; gemm128_out writes y after.
  u16* Xq  = (u16*)aw;
  u16* Xk  = Xq + SZ;
  u16* Xv  = (u16*)y;
  u16* Vtg = (u16*)y;

  // single fused conversion pass: weights (y=0,1) + activations (y=2,3,4)
  cvt_all<<<dim3(1024, 5), 256, 0, stream>>>(
      in_proj_w, out_proj_w, query, key_t, value,
      wqkvb, woutb, Xq, Xk, Xv,
      (3 * E_DIM * E_DIM) / 4, (E_DIM * E_DIM) / 4, (int)(SZ / 4));

  // QKV projection: 32 m-tiles x 4 n-tiles x 3 z = 384 blocks (%8==0); 256^2 8-phase
  gemm_qkv<<<384, 512, 0, stream>>>(
      Xq, Xk, Xv, wqkvb, in_proj_b, Qb, 4, 32);

  transpose_v<<<dim3(4, 16, 8), 256, 0, stream>>>(Vb, Vtg);

  // attn_fwd: 8 qt(128) x 16 h x 8 b = 1024 blocks, 512 threads
  attn_fwd<<<1024, 512, 0, stream>>>(Qb, Kb, Vtg, attnb, rden);

  // aw: 8 b x 8 q-tiles(128) x 8 k-chunks(128) = 512 blocks
  attn_wts<<<512, 256, 0, stream>>>(Qb, Kb, rden, aw);

  // out-proj + bias + residual: 64 m x 8 n = 512 blocks (full machine)
  gemm128_out<<<512, 256, 0, stream>>>(attnb, woutb, out_proj_b, query, y, 8, 64);

  ln_kernel<<<8192, 256, 0, stream>>>(y, ln_gamma, ln_beta);
}